// Round 2
// baseline (1005.494 us; speedup 1.0000x reference)
//
#include <hip/hip_runtime.h>

// GINELayer: scatter-mean message passing + node MLP + residual + BatchNorm + ReLU
// N=50000 nodes, E=1.6M edges, C=128 channels, all fp32.
// edge_index arrives as int32 (harness converts integer inputs to int).

#define C 128
#define BM 64
#define LDA 132   // padded row stride for LDS tiles

// ---------------------------------------------------------------------------
// K1: scatter. Block = 256 threads = 2 channel-groups of 128. 64 edges/block.
// Thread = one channel of one edge. fp32 atomics into aggr.
// ---------------------------------------------------------------------------
__global__ __launch_bounds__(256) void scatter_kernel(
    const float* __restrict__ x, const int* __restrict__ ei,
    const float* __restrict__ eattr, const float* __restrict__ ew,
    const float* __restrict__ eb, float* __restrict__ aggr,
    float* __restrict__ cnt, int E) {
  const int c = threadIdx.x & 127;
  const int half = threadIdx.x >> 7;
  const float wv = ew[c];
  const float bv = eb[c];
  const int e0 = blockIdx.x * 64;
  for (int i = 0; i < 64; i += 2) {
    const int e = e0 + i + half;
    if (e < E) {
      const int src = ei[e];
      const int dst = ei[E + e];
      const float attr = eattr[e];
      const float val = x[src * C + c] + attr * wv + bv;
      atomicAdd(&aggr[dst * C + c], val);
      if (c == 0) atomicAdd(&cnt[dst], 1.0f);
    }
  }
}

// ---------------------------------------------------------------------------
// K2: fused node MLP: out = relu(h@w1+b1)@w2 + b2 + x@res_w + res_b
// where h = (1+eps)*x + aggr/max(cnt,1).
// Block = 256 threads, BM=64 rows. LDS: Ws 64KB + As 33.8KB = 97.8KB.
// Register blocking 4 rows x 8 cols per thread. As is reused across phases.
// ---------------------------------------------------------------------------
__device__ __forceinline__ void gemm_tile(const float* __restrict__ As,
                                          const float* __restrict__ Ws,
                                          int ty, int tx, float acc[4][8]) {
#pragma unroll 2
  for (int k0 = 0; k0 < C; k0 += 4) {
    float4 av[4];
#pragma unroll
    for (int r = 0; r < 4; ++r)
      av[r] = *(const float4*)&As[(ty * 4 + r) * LDA + k0];
#pragma unroll
    for (int kk = 0; kk < 4; ++kk) {
      const float4 w0 = *(const float4*)&Ws[(k0 + kk) * C + tx * 8];
      const float4 w1v = *(const float4*)&Ws[(k0 + kk) * C + tx * 8 + 4];
#pragma unroll
      for (int r = 0; r < 4; ++r) {
        const float a = ((const float*)&av[r])[kk];
        acc[r][0] += a * w0.x;  acc[r][1] += a * w0.y;
        acc[r][2] += a * w0.z;  acc[r][3] += a * w0.w;
        acc[r][4] += a * w1v.x; acc[r][5] += a * w1v.y;
        acc[r][6] += a * w1v.z; acc[r][7] += a * w1v.w;
      }
    }
  }
}

__global__ __launch_bounds__(256) void mlp_kernel(
    const float* __restrict__ x, const float* __restrict__ aggr,
    const float* __restrict__ cnt, const float* __restrict__ epsp,
    const float* __restrict__ w1, const float* __restrict__ b1,
    const float* __restrict__ w2, const float* __restrict__ b2,
    const float* __restrict__ rw, const float* __restrict__ rb,
    float* __restrict__ out, int N) {
  __shared__ float Ws[C * C];       // 64 KB (weights, reloaded per phase)
  __shared__ float As[BM * LDA];    // 33.8 KB (h tile -> T tile -> x tile)

  const int tid = threadIdx.x;
  const int tx = tid & 15;   // col group: cols tx*8..tx*8+7
  const int ty = tid >> 4;   // row group: rows ty*4..ty*4+3
  const int r0 = blockIdx.x * BM;
  const float epv = 1.0f + epsp[0];

  // stage h = (1+eps)*x + aggr/max(cnt,1) into As; w1 into Ws
#pragma unroll
  for (int j = 0; j < 8; ++j) {
    const int f4 = tid + j * 256;       // 0..2047
    const int r = f4 >> 5;
    const int col = (f4 & 31) << 2;
    const int row = r0 + r;
    float4 h4 = make_float4(0.f, 0.f, 0.f, 0.f);
    if (row < N) {
      const float inv = 1.0f / fmaxf(cnt[row], 1.0f);
      const float4 xv = *(const float4*)&x[row * C + col];
      const float4 av = *(const float4*)&aggr[row * C + col];
      h4.x = epv * xv.x + av.x * inv;
      h4.y = epv * xv.y + av.y * inv;
      h4.z = epv * xv.z + av.z * inv;
      h4.w = epv * xv.w + av.w * inv;
    }
    *(float4*)&As[r * LDA + col] = h4;
  }
#pragma unroll
  for (int j = 0; j < 16; ++j) {
    const int f4 = tid + j * 256;
    ((float4*)Ws)[f4] = ((const float4*)w1)[f4];
  }
  __syncthreads();

  // phase 1: acc = h @ w1
  float acc[4][8];
#pragma unroll
  for (int r = 0; r < 4; ++r)
#pragma unroll
    for (int cc = 0; cc < 8; ++cc) acc[r][cc] = 0.f;
  gemm_tile(As, Ws, ty, tx, acc);
  __syncthreads();  // everyone done reading As/Ws

  // T = relu(acc + b1) -> As (overwrite); w2 -> Ws
  {
    const float4 bv0 = *(const float4*)&b1[tx * 8];
    const float4 bv1 = *(const float4*)&b1[tx * 8 + 4];
    const float bb[8] = {bv0.x, bv0.y, bv0.z, bv0.w, bv1.x, bv1.y, bv1.z, bv1.w};
#pragma unroll
    for (int r = 0; r < 4; ++r) {
      float4 t0, t1;
      t0.x = fmaxf(acc[r][0] + bb[0], 0.f);
      t0.y = fmaxf(acc[r][1] + bb[1], 0.f);
      t0.z = fmaxf(acc[r][2] + bb[2], 0.f);
      t0.w = fmaxf(acc[r][3] + bb[3], 0.f);
      t1.x = fmaxf(acc[r][4] + bb[4], 0.f);
      t1.y = fmaxf(acc[r][5] + bb[5], 0.f);
      t1.z = fmaxf(acc[r][6] + bb[6], 0.f);
      t1.w = fmaxf(acc[r][7] + bb[7], 0.f);
      *(float4*)&As[(ty * 4 + r) * LDA + tx * 8] = t0;
      *(float4*)&As[(ty * 4 + r) * LDA + tx * 8 + 4] = t1;
    }
  }
#pragma unroll
  for (int j = 0; j < 16; ++j) {
    const int f4 = tid + j * 256;
    ((float4*)Ws)[f4] = ((const float4*)w2)[f4];
  }
  __syncthreads();

  // phase 2: acc2 = T @ w2 + b2
  float acc2[4][8];
#pragma unroll
  for (int r = 0; r < 4; ++r)
#pragma unroll
    for (int cc = 0; cc < 8; ++cc) acc2[r][cc] = 0.f;
  gemm_tile(As, Ws, ty, tx, acc2);
  {
    const float4 bv0 = *(const float4*)&b2[tx * 8];
    const float4 bv1 = *(const float4*)&b2[tx * 8 + 4];
#pragma unroll
    for (int r = 0; r < 4; ++r) {
      acc2[r][0] += bv0.x; acc2[r][1] += bv0.y; acc2[r][2] += bv0.z; acc2[r][3] += bv0.w;
      acc2[r][4] += bv1.x; acc2[r][5] += bv1.y; acc2[r][6] += bv1.z; acc2[r][7] += bv1.w;
    }
  }
  __syncthreads();

  // x tile -> As; res_w -> Ws
#pragma unroll
  for (int j = 0; j < 8; ++j) {
    const int f4 = tid + j * 256;
    const int r = f4 >> 5;
    const int col = (f4 & 31) << 2;
    const int row = r0 + r;
    float4 xv = make_float4(0.f, 0.f, 0.f, 0.f);
    if (row < N) xv = *(const float4*)&x[row * C + col];
    *(float4*)&As[r * LDA + col] = xv;
  }
#pragma unroll
  for (int j = 0; j < 16; ++j) {
    const int f4 = tid + j * 256;
    ((float4*)Ws)[f4] = ((const float4*)rw)[f4];
  }
  __syncthreads();

  // phase 3: acc2 += x @ res_w + res_b
  gemm_tile(As, Ws, ty, tx, acc2);
  {
    const float4 bv0 = *(const float4*)&rb[tx * 8];
    const float4 bv1 = *(const float4*)&rb[tx * 8 + 4];
#pragma unroll
    for (int r = 0; r < 4; ++r) {
      acc2[r][0] += bv0.x; acc2[r][1] += bv0.y; acc2[r][2] += bv0.z; acc2[r][3] += bv0.w;
      acc2[r][4] += bv1.x; acc2[r][5] += bv1.y; acc2[r][6] += bv1.z; acc2[r][7] += bv1.w;
    }
  }

  // write out
#pragma unroll
  for (int r = 0; r < 4; ++r) {
    const int row = r0 + ty * 4 + r;
    if (row < N) {
      float4 o0 = make_float4(acc2[r][0], acc2[r][1], acc2[r][2], acc2[r][3]);
      float4 o1 = make_float4(acc2[r][4], acc2[r][5], acc2[r][6], acc2[r][7]);
      *(float4*)&out[row * C + tx * 8] = o0;
      *(float4*)&out[row * C + tx * 8 + 4] = o1;
    }
  }
}

// ---------------------------------------------------------------------------
// K3: BN statistics. 256 blocks; per-block fp32 partials -> double atomics.
// ---------------------------------------------------------------------------
__global__ __launch_bounds__(256) void bnstats_kernel(
    const float* __restrict__ out, double* __restrict__ bnsum,
    double* __restrict__ bnsq, int N) {
  __shared__ float s1[256], s2[256];
  const int tid = threadIdx.x;
  const int c = tid & 127;
  const int half = tid >> 7;
  float s = 0.f, q = 0.f;
  for (int r = blockIdx.x * 2 + half; r < N; r += gridDim.x * 2) {
    const float v = out[r * C + c];
    s += v;
    q += v * v;
  }
  s1[tid] = s;
  s2[tid] = q;
  __syncthreads();
  if (tid < 128) {
    s = s1[tid] + s1[tid + 128];
    q = s2[tid] + s2[tid + 128];
    atomicAdd(&bnsum[c], (double)s);
    atomicAdd(&bnsq[c], (double)q);
  }
}

// ---------------------------------------------------------------------------
// K4: BN apply + ReLU, in place on out.
// ---------------------------------------------------------------------------
__global__ __launch_bounds__(256) void bnapply_kernel(
    float* __restrict__ out, const double* __restrict__ bnsum,
    const double* __restrict__ bnsq, const float* __restrict__ gamma,
    const float* __restrict__ beta, int N) {
  __shared__ float sc[C], sh[C];
  const int tid = threadIdx.x;
  if (tid < C) {
    const float mean = (float)(bnsum[tid] / (double)N);
    const float var = (float)(bnsq[tid] / (double)N) - mean * mean;
    const float rs = rsqrtf(var + 1e-5f);
    const float g = gamma[tid] * rs;
    sc[tid] = g;
    sh[tid] = beta[tid] - mean * g;
  }
  __syncthreads();
  const int total4 = N * (C / 4);
  float4* o4 = (float4*)out;
  for (int f = blockIdx.x * blockDim.x + tid; f < total4;
       f += gridDim.x * blockDim.x) {
    const int c4 = (f & 31) << 2;
    float4 v = o4[f];
    v.x = fmaxf(v.x * sc[c4 + 0] + sh[c4 + 0], 0.f);
    v.y = fmaxf(v.y * sc[c4 + 1] + sh[c4 + 1], 0.f);
    v.z = fmaxf(v.z * sc[c4 + 2] + sh[c4 + 2], 0.f);
    v.w = fmaxf(v.w * sc[c4 + 3] + sh[c4 + 3], 0.f);
    o4[f] = v;
  }
}

// ---------------------------------------------------------------------------
extern "C" void kernel_launch(void* const* d_in, const int* in_sizes, int n_in,
                              void* d_out, int out_size, void* d_ws,
                              size_t ws_size, hipStream_t stream) {
  const float* x = (const float*)d_in[0];
  const int* ei = (const int*)d_in[1];          // int32 (harness-converted)
  const float* eattr = (const float*)d_in[2];
  const float* ew = (const float*)d_in[3];
  const float* eb = (const float*)d_in[4];
  const float* w1 = (const float*)d_in[5];
  const float* b1 = (const float*)d_in[6];
  const float* w2 = (const float*)d_in[7];
  const float* b2 = (const float*)d_in[8];
  const float* rw = (const float*)d_in[9];
  const float* rb = (const float*)d_in[10];
  const float* eps = (const float*)d_in[11];
  const float* gamma = (const float*)d_in[12];
  const float* beta = (const float*)d_in[13];

  const int N = in_sizes[0] / C;
  const int E = in_sizes[2];
  float* out = (float*)d_out;

  // workspace layout
  char* ws = (char*)d_ws;
  float* aggr = (float*)ws;                               // N*C floats
  size_t off = (size_t)N * C * sizeof(float);
  off = (off + 255) & ~(size_t)255;
  float* cnt = (float*)(ws + off);                        // N floats
  off += (size_t)N * sizeof(float);
  off = (off + 255) & ~(size_t)255;
  double* bnsum = (double*)(ws + off);                    // C doubles
  double* bnsq = bnsum + C;                               // C doubles
  const size_t zero_bytes = off + 2 * C * sizeof(double);

  hipMemsetAsync(d_ws, 0, zero_bytes, stream);

  scatter_kernel<<<(E + 63) / 64, 256, 0, stream>>>(x, ei, eattr, ew, eb,
                                                    aggr, cnt, E);
  mlp_kernel<<<(N + BM - 1) / BM, 256, 0, stream>>>(x, aggr, cnt, eps, w1, b1,
                                                    w2, b2, rw, rb, out, N);
  bnstats_kernel<<<256, 256, 0, stream>>>(out, bnsum, bnsq, N);
  bnapply_kernel<<<1024, 256, 0, stream>>>(out, bnsum, bnsq, gamma, beta, N);
}

// Round 6
// 584.564 us; speedup vs baseline: 1.7201x; 1.7201x over previous
//
#include <hip/hip_runtime.h>

// GINELayer: CSR-sorted scatter-mean + fused node MLP + residual + BatchNorm + ReLU
// N=50000, E=1.6M, C=128, fp32. edge_index is int32 (harness-converted).

#define C 128
#define BM 64
#define LDA 132   // padded row stride for LDS tiles

// ---------------------------------------------------------------------------
// S1: degree histogram (int atomics).
// ---------------------------------------------------------------------------
__global__ __launch_bounds__(256) void degree_kernel(
    const int* __restrict__ ei, int* __restrict__ deg, int E) {
  for (int e = blockIdx.x * blockDim.x + threadIdx.x; e < E;
       e += gridDim.x * blockDim.x)
    atomicAdd(&deg[ei[E + e]], 1);
}

// ---------------------------------------------------------------------------
// S2a: per-1024-element block exclusive scan (writes exclusive-in-block) +
// block totals.
// ---------------------------------------------------------------------------
__global__ __launch_bounds__(256) void scan_block_kernel(
    const int* __restrict__ deg, int* __restrict__ tmp, int* __restrict__ bsum,
    int N) {
  __shared__ int s[256];
  const int tid = threadIdx.x;
  const int base = blockIdx.x * 1024 + tid * 4;
  const int v0 = (base + 0 < N) ? deg[base + 0] : 0;
  const int v1 = (base + 1 < N) ? deg[base + 1] : 0;
  const int v2 = (base + 2 < N) ? deg[base + 2] : 0;
  const int v3 = (base + 3 < N) ? deg[base + 3] : 0;
  const int tot = v0 + v1 + v2 + v3;
  s[tid] = tot;
  __syncthreads();
  for (int off = 1; off < 256; off <<= 1) {
    const int t = (tid >= off) ? s[tid - off] : 0;
    __syncthreads();
    s[tid] += t;
    __syncthreads();
  }
  const int excl = s[tid] - tot;
  if (base + 0 < N) tmp[base + 0] = excl;
  if (base + 1 < N) tmp[base + 1] = excl + v0;
  if (base + 2 < N) tmp[base + 2] = excl + v0 + v1;
  if (base + 3 < N) tmp[base + 3] = excl + v0 + v1 + v2;
  if (tid == 255) bsum[blockIdx.x] = s[255];
}

// S2b: serial exclusive scan of block sums (small nb); sets offsets[N]=E.
__global__ void scan_top_kernel(int* __restrict__ bsum, int nb,
                                int* __restrict__ offsets, int N) {
  if (threadIdx.x == 0 && blockIdx.x == 0) {
    int run = 0;
    for (int i = 0; i < nb; ++i) {
      const int v = bsum[i];
      bsum[i] = run;
      run += v;
    }
    offsets[N] = run;  // == E
  }
}

// S2c: add block offsets -> final exclusive offsets; init cursor.
__global__ __launch_bounds__(256) void scan_add_kernel(
    const int* __restrict__ tmp, const int* __restrict__ bsum,
    int* __restrict__ offsets, int* __restrict__ cursor, int N) {
  const int i = blockIdx.x * 256 + threadIdx.x;
  if (i < N) {
    const int o = tmp[i] + bsum[i >> 10];
    offsets[i] = o;
    cursor[i] = o;
  }
}

// ---------------------------------------------------------------------------
// S3: scatter edges into CSR slots. One 8-B record {src, attr} per edge.
// ---------------------------------------------------------------------------
__global__ __launch_bounds__(256) void csr_scatter_kernel(
    const int* __restrict__ ei, const float* __restrict__ eattr,
    int* __restrict__ cursor, uint2* __restrict__ recs, int E) {
  for (int e = blockIdx.x * blockDim.x + threadIdx.x; e < E;
       e += gridDim.x * blockDim.x) {
    const int src = ei[e];
    const int dst = ei[E + e];
    const int pos = atomicAdd(&cursor[dst], 1);
    recs[pos] = make_uint2((unsigned)src, __float_as_uint(eattr[e]));
  }
}

// ---------------------------------------------------------------------------
// S4: per-node aggregation. One wave per node; lane holds 2 channels (float2).
// Emits h = (1+eps)*x + segment_mean(message) directly.
// ---------------------------------------------------------------------------
__global__ __launch_bounds__(256) void aggregate_kernel(
    const float* __restrict__ x, const uint2* __restrict__ recs,
    const int* __restrict__ offsets, const float* __restrict__ ew,
    const float* __restrict__ eb, const float* __restrict__ epsp,
    float* __restrict__ h, int N) {
  const int wave = threadIdx.x >> 6;
  const int lane = threadIdx.x & 63;
  const int n = blockIdx.x * 4 + wave;
  if (n >= N) return;
  const float2 w2 = ((const float2*)ew)[lane];
  const float2 b2 = ((const float2*)eb)[lane];
  const int beg = offsets[n];
  const int end = offsets[n + 1];
  float s0 = 0.f, s1 = 0.f;
  int e = beg;
  for (; e + 1 < end; e += 2) {  // 2 outstanding gathers per wave
    const uint2 ra = recs[e];
    const uint2 rb = recs[e + 1];
    const float2 xa = ((const float2*)x)[(size_t)ra.x * 64 + lane];
    const float2 xb = ((const float2*)x)[(size_t)rb.x * 64 + lane];
    const float aa = __uint_as_float(ra.y);
    const float ab = __uint_as_float(rb.y);
    s0 += xa.x + aa * w2.x + b2.x;
    s1 += xa.y + aa * w2.y + b2.y;
    s0 += xb.x + ab * w2.x + b2.x;
    s1 += xb.y + ab * w2.y + b2.y;
  }
  if (e < end) {
    const uint2 ra = recs[e];
    const float2 xa = ((const float2*)x)[(size_t)ra.x * 64 + lane];
    const float aa = __uint_as_float(ra.y);
    s0 += xa.x + aa * w2.x + b2.x;
    s1 += xa.y + aa * w2.y + b2.y;
  }
  const float inv = 1.0f / fmaxf((float)(end - beg), 1.0f);
  const float epv = 1.0f + epsp[0];
  const float2 xn = ((const float2*)x)[(size_t)n * 64 + lane];
  float2 hv;
  hv.x = epv * xn.x + s0 * inv;
  hv.y = epv * xn.y + s1 * inv;
  ((float2*)h)[(size_t)n * 64 + lane] = hv;
}

// ---------------------------------------------------------------------------
// K2: fused node MLP: out = relu(h@w1+b1)@w2 + b2 + x@res_w + res_b
// Block = 256 threads, BM=64 rows. LDS: Ws 64KB + As 33.8KB.
// ---------------------------------------------------------------------------
__device__ __forceinline__ void gemm_tile(const float* __restrict__ As,
                                          const float* __restrict__ Ws,
                                          int ty, int tx, float acc[4][8]) {
#pragma unroll 2
  for (int k0 = 0; k0 < C; k0 += 4) {
    float4 av[4];
#pragma unroll
    for (int r = 0; r < 4; ++r)
      av[r] = *(const float4*)&As[(ty * 4 + r) * LDA + k0];
#pragma unroll
    for (int kk = 0; kk < 4; ++kk) {
      const float4 w0 = *(const float4*)&Ws[(k0 + kk) * C + tx * 8];
      const float4 w1v = *(const float4*)&Ws[(k0 + kk) * C + tx * 8 + 4];
#pragma unroll
      for (int r = 0; r < 4; ++r) {
        const float a = ((const float*)&av[r])[kk];
        acc[r][0] += a * w0.x;  acc[r][1] += a * w0.y;
        acc[r][2] += a * w0.z;  acc[r][3] += a * w0.w;
        acc[r][4] += a * w1v.x; acc[r][5] += a * w1v.y;
        acc[r][6] += a * w1v.z; acc[r][7] += a * w1v.w;
      }
    }
  }
}

__global__ __launch_bounds__(256) void mlp_kernel(
    const float* __restrict__ h, const float* __restrict__ x,
    const float* __restrict__ w1, const float* __restrict__ b1,
    const float* __restrict__ w2, const float* __restrict__ b2,
    const float* __restrict__ rw, const float* __restrict__ rb,
    float* __restrict__ out, int N) {
  __shared__ float Ws[C * C];     // 64 KB
  __shared__ float As[BM * LDA];  // 33.8 KB (h tile -> T tile -> x tile)

  const int tid = threadIdx.x;
  const int tx = tid & 15;
  const int ty = tid >> 4;
  const int r0 = blockIdx.x * BM;

  // stage h tile into As; w1 into Ws
#pragma unroll
  for (int j = 0; j < 8; ++j) {
    const int f4 = tid + j * 256;
    const int r = f4 >> 5;
    const int col = (f4 & 31) << 2;
    const int row = r0 + r;
    float4 h4 = make_float4(0.f, 0.f, 0.f, 0.f);
    if (row < N) h4 = *(const float4*)&h[(size_t)row * C + col];
    *(float4*)&As[r * LDA + col] = h4;
  }
#pragma unroll
  for (int j = 0; j < 16; ++j) {
    const int f4 = tid + j * 256;
    ((float4*)Ws)[f4] = ((const float4*)w1)[f4];
  }
  __syncthreads();

  // phase 1: acc = h @ w1
  float acc[4][8];
#pragma unroll
  for (int r = 0; r < 4; ++r)
#pragma unroll
    for (int cc = 0; cc < 8; ++cc) acc[r][cc] = 0.f;
  gemm_tile(As, Ws, ty, tx, acc);
  __syncthreads();

  // T = relu(acc + b1) -> As; w2 -> Ws
  {
    const float4 bv0 = *(const float4*)&b1[tx * 8];
    const float4 bv1 = *(const float4*)&b1[tx * 8 + 4];
    const float bb[8] = {bv0.x, bv0.y, bv0.z, bv0.w, bv1.x, bv1.y, bv1.z, bv1.w};
#pragma unroll
    for (int r = 0; r < 4; ++r) {
      float4 t0, t1;
      t0.x = fmaxf(acc[r][0] + bb[0], 0.f);
      t0.y = fmaxf(acc[r][1] + bb[1], 0.f);
      t0.z = fmaxf(acc[r][2] + bb[2], 0.f);
      t0.w = fmaxf(acc[r][3] + bb[3], 0.f);
      t1.x = fmaxf(acc[r][4] + bb[4], 0.f);
      t1.y = fmaxf(acc[r][5] + bb[5], 0.f);
      t1.z = fmaxf(acc[r][6] + bb[6], 0.f);
      t1.w = fmaxf(acc[r][7] + bb[7], 0.f);
      *(float4*)&As[(ty * 4 + r) * LDA + tx * 8] = t0;
      *(float4*)&As[(ty * 4 + r) * LDA + tx * 8 + 4] = t1;
    }
  }
#pragma unroll
  for (int j = 0; j < 16; ++j) {
    const int f4 = tid + j * 256;
    ((float4*)Ws)[f4] = ((const float4*)w2)[f4];
  }
  __syncthreads();

  // phase 2: acc2 = T @ w2 + b2
  float acc2[4][8];
#pragma unroll
  for (int r = 0; r < 4; ++r)
#pragma unroll
    for (int cc = 0; cc < 8; ++cc) acc2[r][cc] = 0.f;
  gemm_tile(As, Ws, ty, tx, acc2);
  {
    const float4 bv0 = *(const float4*)&b2[tx * 8];
    const float4 bv1 = *(const float4*)&b2[tx * 8 + 4];
#pragma unroll
    for (int r = 0; r < 4; ++r) {
      acc2[r][0] += bv0.x; acc2[r][1] += bv0.y; acc2[r][2] += bv0.z; acc2[r][3] += bv0.w;
      acc2[r][4] += bv1.x; acc2[r][5] += bv1.y; acc2[r][6] += bv1.z; acc2[r][7] += bv1.w;
    }
  }
  __syncthreads();

  // x tile -> As; res_w -> Ws
#pragma unroll
  for (int j = 0; j < 8; ++j) {
    const int f4 = tid + j * 256;
    const int r = f4 >> 5;
    const int col = (f4 & 31) << 2;
    const int row = r0 + r;
    float4 xv = make_float4(0.f, 0.f, 0.f, 0.f);
    if (row < N) xv = *(const float4*)&x[(size_t)row * C + col];
    *(float4*)&As[r * LDA + col] = xv;
  }
#pragma unroll
  for (int j = 0; j < 16; ++j) {
    const int f4 = tid + j * 256;
    ((float4*)Ws)[f4] = ((const float4*)rw)[f4];
  }
  __syncthreads();

  // phase 3: acc2 += x @ res_w + res_b
  gemm_tile(As, Ws, ty, tx, acc2);
  {
    const float4 bv0 = *(const float4*)&rb[tx * 8];
    const float4 bv1 = *(const float4*)&rb[tx * 8 + 4];
#pragma unroll
    for (int r = 0; r < 4; ++r) {
      acc2[r][0] += bv0.x; acc2[r][1] += bv0.y; acc2[r][2] += bv0.z; acc2[r][3] += bv0.w;
      acc2[r][4] += bv1.x; acc2[r][5] += bv1.y; acc2[r][6] += bv1.z; acc2[r][7] += bv1.w;
    }
  }

#pragma unroll
  for (int r = 0; r < 4; ++r) {
    const int row = r0 + ty * 4 + r;
    if (row < N) {
      *(float4*)&out[(size_t)row * C + tx * 8] =
          make_float4(acc2[r][0], acc2[r][1], acc2[r][2], acc2[r][3]);
      *(float4*)&out[(size_t)row * C + tx * 8 + 4] =
          make_float4(acc2[r][4], acc2[r][5], acc2[r][6], acc2[r][7]);
    }
  }
}

// ---------------------------------------------------------------------------
// K3: BN statistics. fp32 block partials -> double atomics.
// ---------------------------------------------------------------------------
__global__ __launch_bounds__(256) void bnstats_kernel(
    const float* __restrict__ out, double* __restrict__ bnsum,
    double* __restrict__ bnsq, int N) {
  __shared__ float s1[256], s2[256];
  const int tid = threadIdx.x;
  const int c = tid & 127;
  const int half = tid >> 7;
  float s = 0.f, q = 0.f;
  for (int r = blockIdx.x * 2 + half; r < N; r += gridDim.x * 2) {
    const float v = out[(size_t)r * C + c];
    s += v;
    q += v * v;
  }
  s1[tid] = s;
  s2[tid] = q;
  __syncthreads();
  if (tid < 128) {
    s = s1[tid] + s1[tid + 128];
    q = s2[tid] + s2[tid + 128];
    atomicAdd(&bnsum[c], (double)s);
    atomicAdd(&bnsq[c], (double)q);
  }
}

// ---------------------------------------------------------------------------
// K4: BN apply + ReLU, in place.
// ---------------------------------------------------------------------------
__global__ __launch_bounds__(256) void bnapply_kernel(
    float* __restrict__ out, const double* __restrict__ bnsum,
    const double* __restrict__ bnsq, const float* __restrict__ gamma,
    const float* __restrict__ beta, int N) {
  __shared__ float sc[C], sh[C];
  const int tid = threadIdx.x;
  if (tid < C) {
    const float mean = (float)(bnsum[tid] / (double)N);
    const float var = (float)(bnsq[tid] / (double)N) - mean * mean;
    const float rs = rsqrtf(var + 1e-5f);
    const float g = gamma[tid] * rs;
    sc[tid] = g;
    sh[tid] = beta[tid] - mean * g;
  }
  __syncthreads();
  const int total4 = N * (C / 4);
  float4* o4 = (float4*)out;
  for (int f = blockIdx.x * blockDim.x + tid; f < total4;
       f += gridDim.x * blockDim.x) {
    const int c4 = (f & 31) << 2;
    float4 v = o4[f];
    v.x = fmaxf(v.x * sc[c4 + 0] + sh[c4 + 0], 0.f);
    v.y = fmaxf(v.y * sc[c4 + 1] + sh[c4 + 1], 0.f);
    v.z = fmaxf(v.z * sc[c4 + 2] + sh[c4 + 2], 0.f);
    v.w = fmaxf(v.w * sc[c4 + 3] + sh[c4 + 3], 0.f);
    o4[f] = v;
  }
}

// ---------------------------------------------------------------------------
extern "C" void kernel_launch(void* const* d_in, const int* in_sizes, int n_in,
                              void* d_out, int out_size, void* d_ws,
                              size_t ws_size, hipStream_t stream) {
  const float* x = (const float*)d_in[0];
  const int* ei = (const int*)d_in[1];
  const float* eattr = (const float*)d_in[2];
  const float* ew = (const float*)d_in[3];
  const float* eb = (const float*)d_in[4];
  const float* w1 = (const float*)d_in[5];
  const float* b1 = (const float*)d_in[6];
  const float* w2 = (const float*)d_in[7];
  const float* b2 = (const float*)d_in[8];
  const float* rw = (const float*)d_in[9];
  const float* rb = (const float*)d_in[10];
  const float* eps = (const float*)d_in[11];
  const float* gamma = (const float*)d_in[12];
  const float* beta = (const float*)d_in[13];

  const int N = in_sizes[0] / C;
  const int E = in_sizes[2];
  float* out = (float*)d_out;

  // workspace layout
  char* ws = (char*)d_ws;
  size_t off = 0;
  auto take = [&](size_t bytes) -> void* {
    void* p = ws + off;
    off = (off + bytes + 255) & ~(size_t)255;
    return p;
  };
  int* deg = (int*)take((size_t)N * 4);          // [zeroed]
  double* bnsum = (double*)take(C * 8);          // [zeroed]
  double* bnsq = (double*)take(C * 8);           // [zeroed]
  const size_t zero_bytes = off;
  int* offsets = (int*)take(((size_t)N + 1) * 4);
  int* cursor = (int*)take((size_t)N * 4);
  int* tmp = (int*)take((size_t)N * 4);
  int* bsum = (int*)take(256 * 4);
  uint2* recs = (uint2*)take((size_t)E * 8);
  float* h = (float*)take((size_t)N * C * 4);
  (void)ws_size;

  const int nb = (N + 1023) / 1024;  // scan blocks

  hipMemsetAsync(d_ws, 0, zero_bytes, stream);
  degree_kernel<<<2048, 256, 0, stream>>>(ei, deg, E);
  scan_block_kernel<<<nb, 256, 0, stream>>>(deg, tmp, bsum, N);
  scan_top_kernel<<<1, 64, 0, stream>>>(bsum, nb, offsets, N);
  scan_add_kernel<<<(N + 255) / 256, 256, 0, stream>>>(tmp, bsum, offsets,
                                                       cursor, N);
  csr_scatter_kernel<<<2048, 256, 0, stream>>>(ei, eattr, cursor, recs, E);
  aggregate_kernel<<<(N + 3) / 4, 256, 0, stream>>>(x, recs, offsets, ew, eb,
                                                    eps, h, N);
  mlp_kernel<<<(N + BM - 1) / BM, 256, 0, stream>>>(h, x, w1, b1, w2, b2, rw,
                                                    rb, out, N);
  bnstats_kernel<<<256, 256, 0, stream>>>(out, bnsum, bnsq, N);
  bnapply_kernel<<<1024, 256, 0, stream>>>(out, bnsum, bnsq, gamma, beta, N);
}